// Round 4
// baseline (585.836 us; speedup 1.0000x reference)
//
#include <hip/hip_runtime.h>

#define BATCH 8
#define HH 2048
#define WW 2048
#define NPIX (HH*WW)
#define TOPK 8192
#define NB 16384
#define PEAK_CAP 262144
#define CAND_CAP 16384

// workspace byte offsets
#define OFF_PEAKS  0ull
#define OFF_CANDS  (OFF_PEAKS + (size_t)BATCH*PEAK_CAP*8ull)   // 16 MB
#define OFF_HIST   (OFF_CANDS + (size_t)BATCH*CAND_CAP*8ull)   // +1 MB
#define OFF_SA     (OFF_HIST  + (size_t)BATCH*NB*4ull)
#define OFF_FILL   (OFF_SA    + (size_t)BATCH*NB*4ull)
#define OFF_PCOUNT (OFF_FILL  + (size_t)BATCH*NB*4ull)
#define OFF_END    (OFF_PCOUNT + 64ull + 64ull + 64ull)
#define OFF_NCAND  (OFF_PCOUNT + 64ull)
#define OFF_BSTAR  (OFF_NCAND + 64ull)

__device__ __forceinline__ int bucket_of(float v) {
    int bk = (int)(v * 16384.0f);
    if (bk > NB - 1) bk = NB - 1;
    if (bk < 0) bk = 0;
    return bk;
}

// ---------------- K1: NMS via LDS-staged separable max ----------------
// Tile: 128 out cols x 16 out rows. Block 256 threads. grid (16, 128, 8).
// LDS = 25.2 KB -> 6 blocks/CU (24 waves, 75% occupancy) to cover latency.
// Phase1: float4 tile load (136x20 incl halo) -> LDS raw.
// Phase2: horizontal 5-max -> LDS hm (20 rows x 128 cols, float4-packed).
// Phase3: vertical 5-max + center compare -> peak emit via LDS buffer.
__global__ __launch_bounds__(256) void k_nms(
    const float* __restrict__ scores,
    unsigned long long* __restrict__ peaks,
    unsigned int* __restrict__ hist,
    unsigned int* __restrict__ pcount)
{
    const int b = blockIdx.z;
    const int x0 = blockIdx.x * 128;
    const int y0 = blockIdx.y * 16;
    const float* img = scores + (size_t)b * NPIX;
    const float4* imgq = (const float4*)img;

    __shared__ float4 raw[20 * 34];   // rows y0-2..y0+17, 34 col quads
    __shared__ float4 hmq[20 * 32];   // horizontal 5-max, cols x0..x0+127
    __shared__ unsigned long long lbuf[512];
    __shared__ unsigned int lcnt;
    __shared__ unsigned int lbase;
    if (threadIdx.x == 0) lcnt = 0;

    // ---- phase 1: load tile ----
    const int bq = (x0 - 4) >> 2;  // may be -1 at left edge (clamped per-task)
    for (int i = threadIdx.x; i < 20 * 34; i += 256) {
        const int row = i / 34;
        const int q = i - row * 34;
        int gy = y0 - 2 + row;
        gy = gy < 0 ? 0 : (gy > HH - 1 ? HH - 1 : gy);
        int gq = bq + q;
        gq = gq < 0 ? 0 : (gq > WW / 4 - 1 ? WW / 4 - 1 : gq);
        raw[i] = imgq[(size_t)gy * (WW / 4) + gq];
    }
    __syncthreads();

    // ---- phase 2: horizontal 5-max ----
    for (int i = threadIdx.x; i < 20 * 32; i += 256) {
        const int y = i >> 5;
        const int j = i & 31;
        const float4 A = raw[y * 34 + j];
        const float4 B = raw[y * 34 + j + 1];
        const float4 C = raw[y * 34 + j + 2];
        const float v2 = A.z, v3 = A.w, v4 = B.x, v5 = B.y, v6 = B.z,
                    v7 = B.w, v8 = C.x, v9 = C.y;
        const float p23 = fmaxf(v2, v3), p45 = fmaxf(v4, v5),
                    p67 = fmaxf(v6, v7);
        const float p34 = fmaxf(v3, v4), p56 = fmaxf(v5, v6), p78 = fmaxf(v7, v8);
        float4 o;
        o.x = fmaxf(fmaxf(p23, p45), v6);       // v2..v6
        o.y = fmaxf(fmaxf(p34, p56), v7);       // v3..v7
        o.z = fmaxf(fmaxf(p45, p67), v8);       // v4..v8
        o.w = fmaxf(fmaxf(p56, p78), v9);       // v5..v9
        hmq[y * 32 + j] = o;
    }
    __syncthreads();

    // ---- phase 3: vertical 5-max + compare + emit ----
    for (int i = threadIdx.x; i < 16 * 32; i += 256) {
        const int y = i >> 5;
        const int j = i & 31;
        const float4 h0 = hmq[(y + 0) * 32 + j];
        const float4 h1 = hmq[(y + 1) * 32 + j];
        const float4 h2 = hmq[(y + 2) * 32 + j];
        const float4 h3 = hmq[(y + 3) * 32 + j];
        const float4 h4 = hmq[(y + 4) * 32 + j];
        float4 vm;
        vm.x = fmaxf(fmaxf(fmaxf(h0.x, h1.x), fmaxf(h2.x, h3.x)), h4.x);
        vm.y = fmaxf(fmaxf(fmaxf(h0.y, h1.y), fmaxf(h2.y, h3.y)), h4.y);
        vm.z = fmaxf(fmaxf(fmaxf(h0.z, h1.z), fmaxf(h2.z, h3.z)), h4.z);
        vm.w = fmaxf(fmaxf(fmaxf(h0.w, h1.w), fmaxf(h2.w, h3.w)), h4.w);
        const float4 cen = raw[(y + 2) * 34 + j + 1];  // cols x0+4j..x0+4j+3
        const int oy = y0 + y;
        const bool yok = (oy >= 2) && (oy <= HH - 3);
        const int colb = x0 + 4 * j;
        const float cv[4] = {cen.x, cen.y, cen.z, cen.w};
        const float vv[4] = {vm.x, vm.y, vm.z, vm.w};
#pragma unroll
        for (int t = 0; t < 4; ++t) {
            const int col = colb + t;
            if (yok && col >= 2 && col <= WW - 3 && cv[t] == vv[t]) {
                unsigned int pos = atomicAdd(&lcnt, 1u);
                if (pos < 512u) {
                    unsigned int idx = (unsigned int)(oy * WW + col);
                    lbuf[pos] = ((unsigned long long)__float_as_uint(cv[t]) << 32) |
                                (unsigned long long)(~idx);
                }
            }
        }
    }
    __syncthreads();

    unsigned int cnt = lcnt;
    if (cnt > 512u) cnt = 512u;
    if (threadIdx.x == 0) lbase = atomicAdd(&pcount[b], cnt);
    __syncthreads();
    const unsigned int gbase = lbase;
    for (unsigned int s = threadIdx.x; s < cnt; s += 256) {
        unsigned long long key = lbuf[s];
        unsigned int gpos = gbase + s;
        if (gpos < PEAK_CAP) {
            peaks[(size_t)b * PEAK_CAP + gpos] = key;
            float v = __uint_as_float((unsigned int)(key >> 32));
            atomicAdd(&hist[b * NB + bucket_of(v)], 1u);
        }
    }
}

// ---------------- K2: per-batch suffix scan of histogram, find B* ----------------
// grid: (8), block 256
__global__ __launch_bounds__(256) void k_scan(
    const unsigned int* __restrict__ hist,
    unsigned int* __restrict__ SA,
    unsigned int* __restrict__ ncand,
    unsigned int* __restrict__ bstar)
{
    const int b = blockIdx.x;
    const unsigned int* hb = hist + b * NB;
    unsigned int* sab = SA + b * NB;
    const int t = threadIdx.x;

    __shared__ unsigned int ps[256];
    __shared__ int bmax;

    unsigned int sum = 0;
    for (int i = 0; i < 64; ++i) sum += hb[t * 64 + i];
    ps[t] = sum;
    __syncthreads();
    for (int off = 1; off < 256; off <<= 1) {
        unsigned int v = (t + off < 256) ? ps[t + off] : 0u;
        __syncthreads();
        ps[t] += v;
        __syncthreads();
    }
    unsigned int run = ps[t] - sum;  // strictly above this chunk
    int bst_local = -1;
    for (int i = 63; i >= 0; --i) {
        int bin = t * 64 + i;
        unsigned int hv = hb[bin];
        sab[bin] = run;
        if (run + hv >= TOPK && bst_local < 0) bst_local = bin;
        run += hv;
    }
    if (t == 0) bmax = -1;
    __syncthreads();
    if (bst_local >= 0) atomicMax(&bmax, bst_local);
    __syncthreads();
    if (t == 0) {
        int Bs = bmax < 0 ? 0 : bmax;
        bstar[b] = (unsigned int)Bs;
        unsigned int n = sab[Bs] + hb[Bs];
        if (n > CAND_CAP) n = CAND_CAP;
        ncand[b] = n;
    }
}

// ---------------- K3: filter peaks above threshold into bucket-grouped cands ----------------
// grid: (1024, 8), block 256
__global__ __launch_bounds__(256) void k_filter(
    const unsigned long long* __restrict__ peaks,
    const unsigned int* __restrict__ pcount,
    const unsigned int* __restrict__ bstar,
    const unsigned int* __restrict__ SA,
    unsigned int* __restrict__ fill,
    unsigned long long* __restrict__ cands)
{
    const int b = blockIdx.y;
    unsigned int n = pcount[b];
    if (n > PEAK_CAP) n = PEAK_CAP;
    unsigned int i = blockIdx.x * 256 + threadIdx.x;
    if (i >= n) return;
    unsigned long long key = peaks[(size_t)b * PEAK_CAP + i];
    float v = __uint_as_float((unsigned int)(key >> 32));
    int bk = bucket_of(v);
    if ((unsigned int)bk < bstar[b]) return;
    unsigned int pos = SA[b * NB + bk] + atomicAdd(&fill[b * NB + bk], 1u);
    if (pos < CAND_CAP) cands[(size_t)b * CAND_CAP + pos] = key;
}

// ---------------- K4: exact rank within bucket + per-keypoint outputs ----------------
// grid: (64, 8), block 256
__global__ __launch_bounds__(256) void k_out(
    const float* __restrict__ scores,
    const unsigned long long* __restrict__ cands,
    const unsigned int* __restrict__ ncand,
    const unsigned int* __restrict__ SA,
    const unsigned int* __restrict__ hist,
    float* __restrict__ out)
{
    const int b = blockIdx.y;
    unsigned int n = ncand[b];
    if (n > CAND_CAP) n = CAND_CAP;
    const int base = blockIdx.x * 256;
    const unsigned long long* cb = cands + (size_t)b * CAND_CAP;

    __shared__ unsigned long long seg[1024];  // window [base-384, base+640)
    for (int t = threadIdx.x; t < 1024; t += 256) {
        int gi = base - 384 + t;
        unsigned long long v = 0ull;
        if (gi >= 0 && gi < (int)n) v = cb[gi];
        seg[t] = v;
    }
    __syncthreads();

    unsigned int ci = base + threadIdx.x;
    if (ci >= n) return;

    const unsigned long long key = cb[ci];
    float v = __uint_as_float((unsigned int)(key >> 32));
    const int bk = bucket_of(v);
    const unsigned int seg0 = SA[b * NB + bk];
    const unsigned int len = hist[b * NB + bk];

    unsigned int r = 0;
    if ((int)seg0 >= base - 384 && (int)(seg0 + len) <= base + 640) {
        const int s0 = (int)seg0 - (base - 384);
        for (unsigned int j = 0; j < len; ++j)
            r += (seg[s0 + j] > key) ? 1u : 0u;
    } else {
#pragma unroll 4
        for (unsigned int j = 0; j < len; ++j)
            r += (cb[seg0 + j] > key) ? 1u : 0u;
    }
    const unsigned int rank = seg0 + r;
    if (rank >= TOPK) return;

    const unsigned int idx = ~((unsigned int)(key & 0xFFFFFFFFull));
    const int ky = (int)(idx >> 11);
    const int kx = (int)(idx & (WW - 1));
    const float* img = scores + (size_t)b * NPIX;

    float patch[25];
#pragma unroll
    for (int dy = 0; dy < 5; ++dy) {
#pragma unroll
        for (int dx = 0; dx < 5; ++dx) {
            patch[dy * 5 + dx] = img[(size_t)(ky + dy - 2) * WW + (kx + dx - 2)];
        }
    }
    float mx = patch[0];
#pragma unroll
    for (int p = 1; p < 25; ++p) mx = fmaxf(mx, patch[p]);

    float e[25];
    float s = 0.0f, sx = 0.0f, sy = 0.0f;
#pragma unroll
    for (int p = 0; p < 25; ++p) {
        float ex = expf((patch[p] - mx) * 10.0f);
        e[p] = ex;
        s += ex;
        sx += ex * (float)(p % 5 - 2);
        sy += ex * (float)(p / 5 - 2);
    }
    const float xx = sx / s;
    const float yy = sy / s;

    float dsum = 0.0f;
#pragma unroll
    for (int p = 0; p < 25; ++p) {
        float ddx = ((float)(p % 5 - 2) - xx) * 0.5f;
        float ddy = ((float)(p / 5 - 2) - yy) * 0.5f;
        dsum += e[p] * (ddx * ddx + ddy * ddy);
    }
    const float disp = dsum / s;

    const float kxy_x = ((float)kx + xx) / (float)(WW - 1) * 2.0f - 1.0f;
    const float kxy_y = ((float)ky + yy) / (float)(HH - 1) * 2.0f - 1.0f;

    const float px = (kxy_x + 1.0f) * 0.5f * (float)(WW - 1);
    const float py = (kxy_y + 1.0f) * 0.5f * (float)(HH - 1);
    int x0 = (int)floorf(px); x0 = x0 < 0 ? 0 : (x0 > WW - 1 ? WW - 1 : x0);
    int y0 = (int)floorf(py); y0 = y0 < 0 ? 0 : (y0 > HH - 1 ? HH - 1 : y0);
    int x1 = x0 + 1 > WW - 1 ? WW - 1 : x0 + 1;
    int y1 = y0 + 1 > HH - 1 ? HH - 1 : y0 + 1;
    const float wx = px - (float)x0;
    const float wy = py - (float)y0;
    const float v00 = img[(size_t)y0 * WW + x0];
    const float v01 = img[(size_t)y0 * WW + x1];
    const float v10 = img[(size_t)y1 * WW + x0];
    const float v11 = img[(size_t)y1 * WW + x1];
    const float ksc = v00 * (1.0f - wx) * (1.0f - wy) + v01 * wx * (1.0f - wy)
                    + v10 * (1.0f - wx) * wy + v11 * wx * wy;

    const size_t ok = (size_t)b * TOPK + rank;
    out[2 * ok]     = kxy_x;
    out[2 * ok + 1] = kxy_y;
    out[(size_t)BATCH * TOPK * 2 + ok] = ksc;
    out[(size_t)BATCH * TOPK * 3 + ok] = disp;
}

extern "C" void kernel_launch(void* const* d_in, const int* in_sizes, int n_in,
                              void* d_out, int out_size, void* d_ws, size_t ws_size,
                              hipStream_t stream) {
    const float* scores = (const float*)d_in[0];
    float* out = (float*)d_out;
    char* ws = (char*)d_ws;

    unsigned long long* peaks = (unsigned long long*)(ws + OFF_PEAKS);
    unsigned long long* cands = (unsigned long long*)(ws + OFF_CANDS);
    unsigned int* hist   = (unsigned int*)(ws + OFF_HIST);
    unsigned int* SA     = (unsigned int*)(ws + OFF_SA);
    unsigned int* fill   = (unsigned int*)(ws + OFF_FILL);
    unsigned int* pcount = (unsigned int*)(ws + OFF_PCOUNT);
    unsigned int* ncand  = (unsigned int*)(ws + OFF_NCAND);
    unsigned int* bstar  = (unsigned int*)(ws + OFF_BSTAR);

    hipMemsetAsync(ws + OFF_HIST, 0, (size_t)(OFF_END - OFF_HIST), stream);

    k_nms<<<dim3(WW / 128, HH / 16, BATCH), 256, 0, stream>>>(scores, peaks, hist, pcount);
    k_scan<<<dim3(BATCH), 256, 0, stream>>>(hist, SA, ncand, bstar);
    k_filter<<<dim3(PEAK_CAP / 256, BATCH), 256, 0, stream>>>(peaks, pcount, bstar, SA, fill, cands);
    k_out<<<dim3(CAND_CAP / 256, BATCH), 256, 0, stream>>>(scores, cands, ncand, SA, hist, out);
}

// Round 5
// 519.130 us; speedup vs baseline: 1.1285x; 1.1285x over previous
//
#include <hip/hip_runtime.h>

#define BATCH 8
#define HH 2048
#define WW 2048
#define NPIX (HH*WW)
#define TOPK 8192
#define NB 16384
#define PEAK_CAP 196608
#define CHUNK 32768
#define NCHUNK 6
#define CAND_CAP 16384

// workspace byte offsets
#define OFF_PEAKS  0ull
#define OFF_CANDS  (OFF_PEAKS + (size_t)BATCH*PEAK_CAP*8ull)     // 12 MB
#define OFF_HIST   (OFF_CANDS + (size_t)BATCH*CAND_CAP*8ull)     // +1 MB
#define OFF_SA     (OFF_HIST  + (size_t)BATCH*NB*4ull)
#define OFF_FILL   (OFF_SA    + (size_t)BATCH*NB*4ull)
#define OFF_PCOUNT (OFF_FILL  + (size_t)BATCH*NB*4ull)
#define OFF_NCAND  (OFF_PCOUNT + 64ull)
#define OFF_BSTAR  (OFF_NCAND + 64ull)
#define OFF_END    (OFF_PCOUNT + 192ull)
#define OFF_PART   (OFF_PCOUNT + 256ull)
// partials: BATCH * NCHUNK * (NB/2) u32 = 1.5 MB ; total ws ~16 MB

__device__ __forceinline__ int bucket_of(float v) {
    int bk = (int)(v * 16384.0f);
    if (bk > NB - 1) bk = NB - 1;
    if (bk < 0) bk = 0;
    return bk;
}

// ---------------- K1: NMS via LDS-staged separable max (peaks only) ----------------
// Tile: 128 out cols x 16 out rows. Block 256 threads. grid (16, 128, 8).
// NO per-peak global atomics (R4: they were the bottleneck — hist moved to k_hist).
__global__ __launch_bounds__(256) void k_nms(
    const float* __restrict__ scores,
    unsigned long long* __restrict__ peaks,
    unsigned int* __restrict__ pcount)
{
    const int b = blockIdx.z;
    const int x0 = blockIdx.x * 128;
    const int y0 = blockIdx.y * 16;
    const float* img = scores + (size_t)b * NPIX;
    const float4* imgq = (const float4*)img;

    __shared__ float4 raw[20 * 34];   // rows y0-2..y0+17, 34 col quads
    __shared__ float4 hmq[20 * 32];   // horizontal 5-max, cols x0..x0+127
    __shared__ unsigned long long lbuf[512];
    __shared__ unsigned int lcnt;
    __shared__ unsigned int lbase;
    if (threadIdx.x == 0) lcnt = 0;

    // ---- phase 1: load tile ----
    const int bq = (x0 - 4) >> 2;
    for (int i = threadIdx.x; i < 20 * 34; i += 256) {
        const int row = i / 34;
        const int q = i - row * 34;
        int gy = y0 - 2 + row;
        gy = gy < 0 ? 0 : (gy > HH - 1 ? HH - 1 : gy);
        int gq = bq + q;
        gq = gq < 0 ? 0 : (gq > WW / 4 - 1 ? WW / 4 - 1 : gq);
        raw[i] = imgq[(size_t)gy * (WW / 4) + gq];
    }
    __syncthreads();

    // ---- phase 2: horizontal 5-max ----
    for (int i = threadIdx.x; i < 20 * 32; i += 256) {
        const int y = i >> 5;
        const int j = i & 31;
        const float4 A = raw[y * 34 + j];
        const float4 B = raw[y * 34 + j + 1];
        const float4 C = raw[y * 34 + j + 2];
        const float v2 = A.z, v3 = A.w, v4 = B.x, v5 = B.y, v6 = B.z,
                    v7 = B.w, v8 = C.x, v9 = C.y;
        const float p23 = fmaxf(v2, v3), p45 = fmaxf(v4, v5),
                    p67 = fmaxf(v6, v7);
        const float p34 = fmaxf(v3, v4), p56 = fmaxf(v5, v6), p78 = fmaxf(v7, v8);
        float4 o;
        o.x = fmaxf(fmaxf(p23, p45), v6);       // v2..v6
        o.y = fmaxf(fmaxf(p34, p56), v7);       // v3..v7
        o.z = fmaxf(fmaxf(p45, p67), v8);       // v4..v8
        o.w = fmaxf(fmaxf(p56, p78), v9);       // v5..v9
        hmq[y * 32 + j] = o;
    }
    __syncthreads();

    // ---- phase 3: vertical 5-max + compare + emit ----
    for (int i = threadIdx.x; i < 16 * 32; i += 256) {
        const int y = i >> 5;
        const int j = i & 31;
        const float4 h0 = hmq[(y + 0) * 32 + j];
        const float4 h1 = hmq[(y + 1) * 32 + j];
        const float4 h2 = hmq[(y + 2) * 32 + j];
        const float4 h3 = hmq[(y + 3) * 32 + j];
        const float4 h4 = hmq[(y + 4) * 32 + j];
        float4 vm;
        vm.x = fmaxf(fmaxf(fmaxf(h0.x, h1.x), fmaxf(h2.x, h3.x)), h4.x);
        vm.y = fmaxf(fmaxf(fmaxf(h0.y, h1.y), fmaxf(h2.y, h3.y)), h4.y);
        vm.z = fmaxf(fmaxf(fmaxf(h0.z, h1.z), fmaxf(h2.z, h3.z)), h4.z);
        vm.w = fmaxf(fmaxf(fmaxf(h0.w, h1.w), fmaxf(h2.w, h3.w)), h4.w);
        const float4 cen = raw[(y + 2) * 34 + j + 1];
        const int oy = y0 + y;
        const bool yok = (oy >= 2) && (oy <= HH - 3);
        const int colb = x0 + 4 * j;
        const float cv[4] = {cen.x, cen.y, cen.z, cen.w};
        const float vv[4] = {vm.x, vm.y, vm.z, vm.w};
#pragma unroll
        for (int t = 0; t < 4; ++t) {
            const int col = colb + t;
            if (yok && col >= 2 && col <= WW - 3 && cv[t] == vv[t]) {
                unsigned int pos = atomicAdd(&lcnt, 1u);
                if (pos < 512u) {
                    unsigned int idx = (unsigned int)(oy * WW + col);
                    lbuf[pos] = ((unsigned long long)__float_as_uint(cv[t]) << 32) |
                                (unsigned long long)(~idx);
                }
            }
        }
    }
    __syncthreads();

    unsigned int cnt = lcnt;
    if (cnt > 512u) cnt = 512u;
    if (threadIdx.x == 0) lbase = atomicAdd(&pcount[b], cnt);
    __syncthreads();
    const unsigned int gbase = lbase;
    for (unsigned int s = threadIdx.x; s < cnt; s += 256) {
        unsigned int gpos = gbase + s;
        if (gpos < PEAK_CAP) peaks[(size_t)b * PEAK_CAP + gpos] = lbuf[s];
    }
}

// ---------------- K1b: per-chunk LDS-private histogram (no global atomics) ----------------
// grid (NCHUNK, BATCH), block 256. Packed 2 x u16 bins per u32 (chunk<=32768 fits u16).
__global__ __launch_bounds__(256) void k_hist(
    const unsigned long long* __restrict__ peaks,
    const unsigned int* __restrict__ pcount,
    unsigned int* __restrict__ partials)
{
    const int b = blockIdx.y;
    const int blk = blockIdx.x;
    unsigned int n = pcount[b];
    if (n > PEAK_CAP) n = PEAK_CAP;
    const unsigned int base = blk * CHUNK;
    if (base >= n) return;

    __shared__ unsigned int h[NB / 2];   // 32 KB
    for (int w = threadIdx.x; w < NB / 2; w += 256) h[w] = 0u;
    __syncthreads();

    const unsigned int end = (base + CHUNK < n) ? base + CHUNK : n;
    for (unsigned int i = base + threadIdx.x; i < end; i += 256) {
        unsigned long long key = peaks[(size_t)b * PEAK_CAP + i];
        float v = __uint_as_float((unsigned int)(key >> 32));
        int bk = bucket_of(v);
        atomicAdd(&h[bk >> 1], (bk & 1) ? 0x10000u : 1u);
    }
    __syncthreads();

    unsigned int* dst = partials + ((size_t)(b * NCHUNK + blk)) * (NB / 2);
    for (int w = threadIdx.x; w < NB / 2; w += 256) dst[w] = h[w];
}

// ---------------- K2: merge partials + suffix scan, find B* ----------------
// grid: (8), block 256
__global__ __launch_bounds__(256) void k_scan(
    const unsigned int* __restrict__ partials,
    const unsigned int* __restrict__ pcount,
    unsigned int* __restrict__ hist,
    unsigned int* __restrict__ SA,
    unsigned int* __restrict__ ncand,
    unsigned int* __restrict__ bstar)
{
    const int b = blockIdx.x;
    unsigned int n = pcount[b];
    if (n > PEAK_CAP) n = PEAK_CAP;
    const int nblk = (int)((n + CHUNK - 1) / CHUNK);
    unsigned int* hb = hist + b * NB;
    unsigned int* sab = SA + b * NB;
    const int t = threadIdx.x;

    __shared__ unsigned int ps[256];
    __shared__ int bmax;

    // merge partials -> hist, accumulate this thread's 64-bin total
    unsigned int sum = 0;
    for (int i = 0; i < 32; ++i) {
        const int w = t * 32 + i;
        unsigned int lo = 0, hi = 0;
        for (int k = 0; k < nblk; ++k) {
            unsigned int p = partials[(size_t)(b * NCHUNK + k) * (NB / 2) + w];
            lo += p & 0xFFFFu;
            hi += p >> 16;
        }
        hb[2 * w] = lo;
        hb[2 * w + 1] = hi;
        sum += lo + hi;
    }
    ps[t] = sum;
    __syncthreads();
    for (int off = 1; off < 256; off <<= 1) {
        unsigned int v = (t + off < 256) ? ps[t + off] : 0u;
        __syncthreads();
        ps[t] += v;
        __syncthreads();
    }
    unsigned int run = ps[t] - sum;  // strictly above this chunk
    int bst_local = -1;
    for (int i = 63; i >= 0; --i) {
        int bin = t * 64 + i;
        unsigned int hv = hb[bin];
        sab[bin] = run;
        if (run + hv >= TOPK && bst_local < 0) bst_local = bin;
        run += hv;
    }
    if (t == 0) bmax = -1;
    __syncthreads();
    if (bst_local >= 0) atomicMax(&bmax, bst_local);
    __syncthreads();
    if (t == 0) {
        int Bs = bmax < 0 ? 0 : bmax;
        bstar[b] = (unsigned int)Bs;
        unsigned int nc = sab[Bs] + hb[Bs];
        if (nc > CAND_CAP) nc = CAND_CAP;
        ncand[b] = nc;
    }
}

// ---------------- K3: filter peaks above threshold into bucket-grouped cands ----------------
// grid: (768, 8), block 256
__global__ __launch_bounds__(256) void k_filter(
    const unsigned long long* __restrict__ peaks,
    const unsigned int* __restrict__ pcount,
    const unsigned int* __restrict__ bstar,
    const unsigned int* __restrict__ SA,
    unsigned int* __restrict__ fill,
    unsigned long long* __restrict__ cands)
{
    const int b = blockIdx.y;
    unsigned int n = pcount[b];
    if (n > PEAK_CAP) n = PEAK_CAP;
    unsigned int i = blockIdx.x * 256 + threadIdx.x;
    if (i >= n) return;
    unsigned long long key = peaks[(size_t)b * PEAK_CAP + i];
    float v = __uint_as_float((unsigned int)(key >> 32));
    int bk = bucket_of(v);
    if ((unsigned int)bk < bstar[b]) return;
    unsigned int pos = SA[b * NB + bk] + atomicAdd(&fill[b * NB + bk], 1u);
    if (pos < CAND_CAP) cands[(size_t)b * CAND_CAP + pos] = key;
}

// ---------------- K4: exact rank within bucket + per-keypoint outputs ----------------
// grid: (64, 8), block 256
__global__ __launch_bounds__(256) void k_out(
    const float* __restrict__ scores,
    const unsigned long long* __restrict__ cands,
    const unsigned int* __restrict__ ncand,
    const unsigned int* __restrict__ SA,
    const unsigned int* __restrict__ hist,
    float* __restrict__ out)
{
    const int b = blockIdx.y;
    unsigned int n = ncand[b];
    if (n > CAND_CAP) n = CAND_CAP;
    const int base = blockIdx.x * 256;
    const unsigned long long* cb = cands + (size_t)b * CAND_CAP;

    __shared__ unsigned long long seg[1024];  // window [base-384, base+640)
    for (int t = threadIdx.x; t < 1024; t += 256) {
        int gi = base - 384 + t;
        unsigned long long v = 0ull;
        if (gi >= 0 && gi < (int)n) v = cb[gi];
        seg[t] = v;
    }
    __syncthreads();

    unsigned int ci = base + threadIdx.x;
    if (ci >= n) return;

    const unsigned long long key = cb[ci];
    float v = __uint_as_float((unsigned int)(key >> 32));
    const int bk = bucket_of(v);
    const unsigned int seg0 = SA[b * NB + bk];
    const unsigned int len = hist[b * NB + bk];

    unsigned int r = 0;
    if ((int)seg0 >= base - 384 && (int)(seg0 + len) <= base + 640) {
        const int s0 = (int)seg0 - (base - 384);
        for (unsigned int j = 0; j < len; ++j)
            r += (seg[s0 + j] > key) ? 1u : 0u;
    } else {
#pragma unroll 4
        for (unsigned int j = 0; j < len; ++j)
            r += (cb[seg0 + j] > key) ? 1u : 0u;
    }
    const unsigned int rank = seg0 + r;
    if (rank >= TOPK) return;

    const unsigned int idx = ~((unsigned int)(key & 0xFFFFFFFFull));
    const int ky = (int)(idx >> 11);
    const int kx = (int)(idx & (WW - 1));
    const float* img = scores + (size_t)b * NPIX;

    float patch[25];
#pragma unroll
    for (int dy = 0; dy < 5; ++dy) {
#pragma unroll
        for (int dx = 0; dx < 5; ++dx) {
            patch[dy * 5 + dx] = img[(size_t)(ky + dy - 2) * WW + (kx + dx - 2)];
        }
    }
    float mx = patch[0];
#pragma unroll
    for (int p = 1; p < 25; ++p) mx = fmaxf(mx, patch[p]);

    float e[25];
    float s = 0.0f, sx = 0.0f, sy = 0.0f;
#pragma unroll
    for (int p = 0; p < 25; ++p) {
        float ex = expf((patch[p] - mx) * 10.0f);
        e[p] = ex;
        s += ex;
        sx += ex * (float)(p % 5 - 2);
        sy += ex * (float)(p / 5 - 2);
    }
    const float xx = sx / s;
    const float yy = sy / s;

    float dsum = 0.0f;
#pragma unroll
    for (int p = 0; p < 25; ++p) {
        float ddx = ((float)(p % 5 - 2) - xx) * 0.5f;
        float ddy = ((float)(p / 5 - 2) - yy) * 0.5f;
        dsum += e[p] * (ddx * ddx + ddy * ddy);
    }
    const float disp = dsum / s;

    const float kxy_x = ((float)kx + xx) / (float)(WW - 1) * 2.0f - 1.0f;
    const float kxy_y = ((float)ky + yy) / (float)(HH - 1) * 2.0f - 1.0f;

    const float px = (kxy_x + 1.0f) * 0.5f * (float)(WW - 1);
    const float py = (kxy_y + 1.0f) * 0.5f * (float)(HH - 1);
    int x0 = (int)floorf(px); x0 = x0 < 0 ? 0 : (x0 > WW - 1 ? WW - 1 : x0);
    int y0 = (int)floorf(py); y0 = y0 < 0 ? 0 : (y0 > HH - 1 ? HH - 1 : y0);
    int x1 = x0 + 1 > WW - 1 ? WW - 1 : x0 + 1;
    int y1 = y0 + 1 > HH - 1 ? HH - 1 : y0 + 1;
    const float wx = px - (float)x0;
    const float wy = py - (float)y0;
    const float v00 = img[(size_t)y0 * WW + x0];
    const float v01 = img[(size_t)y0 * WW + x1];
    const float v10 = img[(size_t)y1 * WW + x0];
    const float v11 = img[(size_t)y1 * WW + x1];
    const float ksc = v00 * (1.0f - wx) * (1.0f - wy) + v01 * wx * (1.0f - wy)
                    + v10 * (1.0f - wx) * wy + v11 * wx * wy;

    const size_t ok = (size_t)b * TOPK + rank;
    out[2 * ok]     = kxy_x;
    out[2 * ok + 1] = kxy_y;
    out[(size_t)BATCH * TOPK * 2 + ok] = ksc;
    out[(size_t)BATCH * TOPK * 3 + ok] = disp;
}

extern "C" void kernel_launch(void* const* d_in, const int* in_sizes, int n_in,
                              void* d_out, int out_size, void* d_ws, size_t ws_size,
                              hipStream_t stream) {
    const float* scores = (const float*)d_in[0];
    float* out = (float*)d_out;
    char* ws = (char*)d_ws;

    unsigned long long* peaks = (unsigned long long*)(ws + OFF_PEAKS);
    unsigned long long* cands = (unsigned long long*)(ws + OFF_CANDS);
    unsigned int* hist   = (unsigned int*)(ws + OFF_HIST);
    unsigned int* SA     = (unsigned int*)(ws + OFF_SA);
    unsigned int* fill   = (unsigned int*)(ws + OFF_FILL);
    unsigned int* pcount = (unsigned int*)(ws + OFF_PCOUNT);
    unsigned int* ncand  = (unsigned int*)(ws + OFF_NCAND);
    unsigned int* bstar  = (unsigned int*)(ws + OFF_BSTAR);
    unsigned int* part   = (unsigned int*)(ws + OFF_PART);

    // zero fill + counters only (hist/SA are fully overwritten by k_scan)
    hipMemsetAsync(ws + OFF_FILL, 0, (size_t)(OFF_END - OFF_FILL), stream);

    k_nms<<<dim3(WW / 128, HH / 16, BATCH), 256, 0, stream>>>(scores, peaks, pcount);
    k_hist<<<dim3(NCHUNK, BATCH), 256, 0, stream>>>(peaks, pcount, part);
    k_scan<<<dim3(BATCH), 256, 0, stream>>>(part, pcount, hist, SA, ncand, bstar);
    k_filter<<<dim3(PEAK_CAP / 256, BATCH), 256, 0, stream>>>(peaks, pcount, bstar, SA, fill, cands);
    k_out<<<dim3(CAND_CAP / 256, BATCH), 256, 0, stream>>>(scores, cands, ncand, SA, hist, out);
}

// Round 6
// 425.583 us; speedup vs baseline: 1.3766x; 1.2198x over previous
//
#include <hip/hip_runtime.h>

#define BATCH 8
#define HH 2048
#define WW 2048
#define NPIX (HH*WW)
#define TOPK 8192
#define NB 16384
#define PEAK_CAP 196608
#define CHUNK 32768
#define NCHUNK 6
#define CAND_CAP 16384

// workspace byte offsets
#define OFF_PEAKS  0ull
#define OFF_CANDS  (OFF_PEAKS + (size_t)BATCH*PEAK_CAP*8ull)     // 12 MB
#define OFF_HIST   (OFF_CANDS + (size_t)BATCH*CAND_CAP*8ull)     // +1 MB
#define OFF_SA     (OFF_HIST  + (size_t)BATCH*NB*4ull)
#define OFF_FILL   (OFF_SA    + (size_t)BATCH*NB*4ull)
#define OFF_PCOUNT (OFF_FILL  + (size_t)BATCH*NB*4ull)
#define OFF_NCAND  (OFF_PCOUNT + 64ull)
#define OFF_BSTAR  (OFF_NCAND + 64ull)
#define OFF_END    (OFF_PCOUNT + 192ull)
#define OFF_PART   (OFF_PCOUNT + 256ull)
// partials: BATCH * NCHUNK * (NB/2) u32 = 1.5 MB ; total ws ~16 MB

__device__ __forceinline__ int bucket_of(float v) {
    int bk = (int)(v * 16384.0f);
    if (bk > NB - 1) bk = NB - 1;
    if (bk < 0) bk = 0;
    return bk;
}

// ---------------- K1: NMS, register-direct (no LDS staging) ----------------
// Block 256 threads as 16x16; each thread: 4 cols x 4 rows from 24 float4
// global loads (L1 covers the 6x overlap). All max-reduction in registers,
// static unrolls only (R1 lesson: no dynamic ring indices). LDS = 4KB append
// buffer only. grid (32, 32, 8).
__global__ __launch_bounds__(256) void k_nms(
    const float* __restrict__ scores,
    unsigned long long* __restrict__ peaks,
    unsigned int* __restrict__ pcount)
{
    const int b = blockIdx.z;
    const int tx = threadIdx.x & 15;
    const int ty = threadIdx.x >> 4;
    const int x = blockIdx.x * 64 + tx * 4;   // first owned col
    const int y = blockIdx.y * 64 + ty * 4;   // first owned row
    const float* img = scores + (size_t)b * NPIX;
    const float4* imgq = (const float4*)img;

    __shared__ unsigned long long lbuf[512];
    __shared__ unsigned int lcnt;
    __shared__ unsigned int lbase;
    if (threadIdx.x == 0) lcnt = 0;
    __syncthreads();

    const int q = x >> 2;
    const int qm = (q > 0) ? q - 1 : 0;
    const int qp = (q < WW / 4 - 1) ? q + 1 : WW / 4 - 1;

    float hm[8][4];   // horizontal 5-max for loaded rows j=0..7 (rows y-2..y+5)
    float c4[4][4];   // center values for rows y..y+3 (loaded rows j=2..5)

#pragma unroll
    for (int j = 0; j < 8; ++j) {
        int gy = y - 2 + j;
        gy = gy < 0 ? 0 : (gy > HH - 1 ? HH - 1 : gy);
        const float4* rowq = imgq + (size_t)gy * (WW / 4);
        const float4 A = rowq[qm];
        const float4 B = rowq[q];
        const float4 C = rowq[qp];
        const float v[12] = {A.x, A.y, A.z, A.w, B.x, B.y, B.z, B.w,
                             C.x, C.y, C.z, C.w};
        // hm[j][i] = max(v[2+i .. 6+i])
        float aa[8];
#pragma unroll
        for (int k = 0; k < 8; ++k) aa[k] = fmaxf(v[k + 2], v[k + 3]);
#pragma unroll
        for (int i = 0; i < 4; ++i)
            hm[j][i] = fmaxf(fmaxf(aa[i], aa[i + 2]), v[i + 6]);
        if (j >= 2 && j <= 5) {
#pragma unroll
            for (int i = 0; i < 4; ++i) c4[j - 2][i] = v[i + 4];
        }
    }

#pragma unroll
    for (int r = 0; r < 4; ++r) {
        const int oy = y + r;
        const bool yok = (oy >= 2) && (oy <= HH - 3);
#pragma unroll
        for (int i = 0; i < 4; ++i) {
            const float vm = fmaxf(fmaxf(fmaxf(hm[r][i], hm[r + 1][i]),
                                         fmaxf(hm[r + 2][i], hm[r + 3][i])),
                                   hm[r + 4][i]);
            const float cv = c4[r][i];
            const int col = x + i;
            if (yok && col >= 2 && col <= WW - 3 && cv == vm) {
                unsigned int pos = atomicAdd(&lcnt, 1u);
                if (pos < 512u) {
                    unsigned int idx = (unsigned int)(oy * WW + col);
                    lbuf[pos] = ((unsigned long long)__float_as_uint(cv) << 32) |
                                (unsigned long long)(~idx);
                }
            }
        }
    }
    __syncthreads();

    unsigned int cnt = lcnt;
    if (cnt > 512u) cnt = 512u;
    if (threadIdx.x == 0) lbase = atomicAdd(&pcount[b], cnt);
    __syncthreads();
    const unsigned int gbase = lbase;
    for (unsigned int s = threadIdx.x; s < cnt; s += 256) {
        unsigned int gpos = gbase + s;
        if (gpos < PEAK_CAP) peaks[(size_t)b * PEAK_CAP + gpos] = lbuf[s];
    }
}

// ---------------- K1b: per-chunk LDS-private histogram (no global atomics) ----------------
// grid (NCHUNK, BATCH), block 256. Packed 2 x u16 bins per u32 (chunk<=32768 fits u16).
__global__ __launch_bounds__(256) void k_hist(
    const unsigned long long* __restrict__ peaks,
    const unsigned int* __restrict__ pcount,
    unsigned int* __restrict__ partials)
{
    const int b = blockIdx.y;
    const int blk = blockIdx.x;
    unsigned int n = pcount[b];
    if (n > PEAK_CAP) n = PEAK_CAP;
    const unsigned int base = blk * CHUNK;
    if (base >= n) return;

    __shared__ unsigned int h[NB / 2];   // 32 KB
    for (int w = threadIdx.x; w < NB / 2; w += 256) h[w] = 0u;
    __syncthreads();

    const unsigned int end = (base + CHUNK < n) ? base + CHUNK : n;
    for (unsigned int i = base + threadIdx.x; i < end; i += 256) {
        unsigned long long key = peaks[(size_t)b * PEAK_CAP + i];
        float v = __uint_as_float((unsigned int)(key >> 32));
        int bk = bucket_of(v);
        atomicAdd(&h[bk >> 1], (bk & 1) ? 0x10000u : 1u);
    }
    __syncthreads();

    unsigned int* dst = partials + ((size_t)(b * NCHUNK + blk)) * (NB / 2);
    for (int w = threadIdx.x; w < NB / 2; w += 256) dst[w] = h[w];
}

// ---------------- K2: merge partials + suffix scan, find B* ----------------
// grid: (8), block 256
__global__ __launch_bounds__(256) void k_scan(
    const unsigned int* __restrict__ partials,
    const unsigned int* __restrict__ pcount,
    unsigned int* __restrict__ hist,
    unsigned int* __restrict__ SA,
    unsigned int* __restrict__ ncand,
    unsigned int* __restrict__ bstar)
{
    const int b = blockIdx.x;
    unsigned int n = pcount[b];
    if (n > PEAK_CAP) n = PEAK_CAP;
    const int nblk = (int)((n + CHUNK - 1) / CHUNK);
    unsigned int* hb = hist + b * NB;
    unsigned int* sab = SA + b * NB;
    const int t = threadIdx.x;

    __shared__ unsigned int ps[256];
    __shared__ int bmax;

    unsigned int sum = 0;
    for (int i = 0; i < 32; ++i) {
        const int w = t * 32 + i;
        unsigned int lo = 0, hi = 0;
        for (int k = 0; k < nblk; ++k) {
            unsigned int p = partials[(size_t)(b * NCHUNK + k) * (NB / 2) + w];
            lo += p & 0xFFFFu;
            hi += p >> 16;
        }
        hb[2 * w] = lo;
        hb[2 * w + 1] = hi;
        sum += lo + hi;
    }
    ps[t] = sum;
    __syncthreads();
    for (int off = 1; off < 256; off <<= 1) {
        unsigned int v = (t + off < 256) ? ps[t + off] : 0u;
        __syncthreads();
        ps[t] += v;
        __syncthreads();
    }
    unsigned int run = ps[t] - sum;  // strictly above this chunk
    int bst_local = -1;
    for (int i = 63; i >= 0; --i) {
        int bin = t * 64 + i;
        unsigned int hv = hb[bin];
        sab[bin] = run;
        if (run + hv >= TOPK && bst_local < 0) bst_local = bin;
        run += hv;
    }
    if (t == 0) bmax = -1;
    __syncthreads();
    if (bst_local >= 0) atomicMax(&bmax, bst_local);
    __syncthreads();
    if (t == 0) {
        int Bs = bmax < 0 ? 0 : bmax;
        bstar[b] = (unsigned int)Bs;
        unsigned int nc = sab[Bs] + hb[Bs];
        if (nc > CAND_CAP) nc = CAND_CAP;
        ncand[b] = nc;
    }
}

// ---------------- K3: filter peaks above threshold into bucket-grouped cands ----------------
// grid: (768, 8), block 256
__global__ __launch_bounds__(256) void k_filter(
    const unsigned long long* __restrict__ peaks,
    const unsigned int* __restrict__ pcount,
    const unsigned int* __restrict__ bstar,
    const unsigned int* __restrict__ SA,
    unsigned int* __restrict__ fill,
    unsigned long long* __restrict__ cands)
{
    const int b = blockIdx.y;
    unsigned int n = pcount[b];
    if (n > PEAK_CAP) n = PEAK_CAP;
    unsigned int i = blockIdx.x * 256 + threadIdx.x;
    if (i >= n) return;
    unsigned long long key = peaks[(size_t)b * PEAK_CAP + i];
    float v = __uint_as_float((unsigned int)(key >> 32));
    int bk = bucket_of(v);
    if ((unsigned int)bk < bstar[b]) return;
    unsigned int pos = SA[b * NB + bk] + atomicAdd(&fill[b * NB + bk], 1u);
    if (pos < CAND_CAP) cands[(size_t)b * CAND_CAP + pos] = key;
}

// ---------------- K4: exact rank within bucket + per-keypoint outputs ----------------
// grid: (64, 8), block 256
__global__ __launch_bounds__(256) void k_out(
    const float* __restrict__ scores,
    const unsigned long long* __restrict__ cands,
    const unsigned int* __restrict__ ncand,
    const unsigned int* __restrict__ SA,
    const unsigned int* __restrict__ hist,
    float* __restrict__ out)
{
    const int b = blockIdx.y;
    unsigned int n = ncand[b];
    if (n > CAND_CAP) n = CAND_CAP;
    const int base = blockIdx.x * 256;
    const unsigned long long* cb = cands + (size_t)b * CAND_CAP;

    __shared__ unsigned long long seg[1024];  // window [base-384, base+640)
    for (int t = threadIdx.x; t < 1024; t += 256) {
        int gi = base - 384 + t;
        unsigned long long v = 0ull;
        if (gi >= 0 && gi < (int)n) v = cb[gi];
        seg[t] = v;
    }
    __syncthreads();

    unsigned int ci = base + threadIdx.x;
    if (ci >= n) return;

    const unsigned long long key = cb[ci];
    float v = __uint_as_float((unsigned int)(key >> 32));
    const int bk = bucket_of(v);
    const unsigned int seg0 = SA[b * NB + bk];
    const unsigned int len = hist[b * NB + bk];

    unsigned int r = 0;
    if ((int)seg0 >= base - 384 && (int)(seg0 + len) <= base + 640) {
        const int s0 = (int)seg0 - (base - 384);
        for (unsigned int j = 0; j < len; ++j)
            r += (seg[s0 + j] > key) ? 1u : 0u;
    } else {
#pragma unroll 4
        for (unsigned int j = 0; j < len; ++j)
            r += (cb[seg0 + j] > key) ? 1u : 0u;
    }
    const unsigned int rank = seg0 + r;
    if (rank >= TOPK) return;

    const unsigned int idx = ~((unsigned int)(key & 0xFFFFFFFFull));
    const int ky = (int)(idx >> 11);
    const int kx = (int)(idx & (WW - 1));
    const float* img = scores + (size_t)b * NPIX;

    float patch[25];
#pragma unroll
    for (int dy = 0; dy < 5; ++dy) {
#pragma unroll
        for (int dx = 0; dx < 5; ++dx) {
            patch[dy * 5 + dx] = img[(size_t)(ky + dy - 2) * WW + (kx + dx - 2)];
        }
    }
    float mx = patch[0];
#pragma unroll
    for (int p = 1; p < 25; ++p) mx = fmaxf(mx, patch[p]);

    float e[25];
    float s = 0.0f, sx = 0.0f, sy = 0.0f;
#pragma unroll
    for (int p = 0; p < 25; ++p) {
        float ex = expf((patch[p] - mx) * 10.0f);
        e[p] = ex;
        s += ex;
        sx += ex * (float)(p % 5 - 2);
        sy += ex * (float)(p / 5 - 2);
    }
    const float xx = sx / s;
    const float yy = sy / s;

    float dsum = 0.0f;
#pragma unroll
    for (int p = 0; p < 25; ++p) {
        float ddx = ((float)(p % 5 - 2) - xx) * 0.5f;
        float ddy = ((float)(p / 5 - 2) - yy) * 0.5f;
        dsum += e[p] * (ddx * ddx + ddy * ddy);
    }
    const float disp = dsum / s;

    const float kxy_x = ((float)kx + xx) / (float)(WW - 1) * 2.0f - 1.0f;
    const float kxy_y = ((float)ky + yy) / (float)(HH - 1) * 2.0f - 1.0f;

    const float px = (kxy_x + 1.0f) * 0.5f * (float)(WW - 1);
    const float py = (kxy_y + 1.0f) * 0.5f * (float)(HH - 1);
    int x0 = (int)floorf(px); x0 = x0 < 0 ? 0 : (x0 > WW - 1 ? WW - 1 : x0);
    int y0 = (int)floorf(py); y0 = y0 < 0 ? 0 : (y0 > HH - 1 ? HH - 1 : y0);
    int x1 = x0 + 1 > WW - 1 ? WW - 1 : x0 + 1;
    int y1 = y0 + 1 > HH - 1 ? HH - 1 : y0 + 1;
    const float wx = px - (float)x0;
    const float wy = py - (float)y0;
    const float v00 = img[(size_t)y0 * WW + x0];
    const float v01 = img[(size_t)y0 * WW + x1];
    const float v10 = img[(size_t)y1 * WW + x0];
    const float v11 = img[(size_t)y1 * WW + x1];
    const float ksc = v00 * (1.0f - wx) * (1.0f - wy) + v01 * wx * (1.0f - wy)
                    + v10 * (1.0f - wx) * wy + v11 * wx * wy;

    const size_t ok = (size_t)b * TOPK + rank;
    out[2 * ok]     = kxy_x;
    out[2 * ok + 1] = kxy_y;
    out[(size_t)BATCH * TOPK * 2 + ok] = ksc;
    out[(size_t)BATCH * TOPK * 3 + ok] = disp;
}

extern "C" void kernel_launch(void* const* d_in, const int* in_sizes, int n_in,
                              void* d_out, int out_size, void* d_ws, size_t ws_size,
                              hipStream_t stream) {
    const float* scores = (const float*)d_in[0];
    float* out = (float*)d_out;
    char* ws = (char*)d_ws;

    unsigned long long* peaks = (unsigned long long*)(ws + OFF_PEAKS);
    unsigned long long* cands = (unsigned long long*)(ws + OFF_CANDS);
    unsigned int* hist   = (unsigned int*)(ws + OFF_HIST);
    unsigned int* SA     = (unsigned int*)(ws + OFF_SA);
    unsigned int* fill   = (unsigned int*)(ws + OFF_FILL);
    unsigned int* pcount = (unsigned int*)(ws + OFF_PCOUNT);
    unsigned int* ncand  = (unsigned int*)(ws + OFF_NCAND);
    unsigned int* bstar  = (unsigned int*)(ws + OFF_BSTAR);
    unsigned int* part   = (unsigned int*)(ws + OFF_PART);

    // zero fill + counters only (hist/SA are fully overwritten by k_scan)
    hipMemsetAsync(ws + OFF_FILL, 0, (size_t)(OFF_END - OFF_FILL), stream);

    k_nms<<<dim3(WW / 64, HH / 64, BATCH), 256, 0, stream>>>(scores, peaks, pcount);
    k_hist<<<dim3(NCHUNK, BATCH), 256, 0, stream>>>(peaks, pcount, part);
    k_scan<<<dim3(BATCH), 256, 0, stream>>>(part, pcount, hist, SA, ncand, bstar);
    k_filter<<<dim3(PEAK_CAP / 256, BATCH), 256, 0, stream>>>(peaks, pcount, bstar, SA, fill, cands);
    k_out<<<dim3(CAND_CAP / 256, BATCH), 256, 0, stream>>>(scores, cands, ncand, SA, hist, out);
}

// Round 7
// 358.349 us; speedup vs baseline: 1.6348x; 1.1876x over previous
//
#include <hip/hip_runtime.h>

#define BATCH 8
#define HH 2048
#define WW 2048
#define NPIX (HH*WW)
#define TOPK 8192
#define NB 16384
#define PEAK_CAP 196608
#define CHUNK 32768
#define NCHUNK 6
#define FCHUNK 8192
#define LBINS 2048
#define LO_BIN (NB - LBINS)
#define CAND_CAP 16384

// workspace byte offsets
#define OFF_PEAKS  0ull
#define OFF_CANDS  (OFF_PEAKS + (size_t)BATCH*PEAK_CAP*8ull)     // 12 MB
#define OFF_HIST   (OFF_CANDS + (size_t)BATCH*CAND_CAP*8ull)     // +1 MB
#define OFF_SA     (OFF_HIST  + (size_t)BATCH*NB*4ull)
#define OFF_FILL   (OFF_SA    + (size_t)BATCH*NB*4ull)
#define OFF_PCOUNT (OFF_FILL  + (size_t)BATCH*NB*4ull)
#define OFF_NCAND  (OFF_PCOUNT + 64ull)
#define OFF_BSTAR  (OFF_NCAND + 64ull)
#define OFF_END    (OFF_PCOUNT + 192ull)
#define OFF_PART   (OFF_PCOUNT + 256ull)
// partials: BATCH * NCHUNK * (NB/2) u32 = 1.5 MB ; total ws ~16 MB

__device__ __forceinline__ int bucket_of(float v) {
    int bk = (int)(v * 16384.0f);
    if (bk > NB - 1) bk = NB - 1;
    if (bk < 0) bk = 0;
    return bk;
}

// ---------------- K1: NMS, register-direct (no LDS staging) ----------------
// Block 256 threads as 16x16; each thread: 4 cols x 4 rows from 24 float4
// global loads (L1 covers the 6x overlap). grid (32, 32, 8).
__global__ __launch_bounds__(256) void k_nms(
    const float* __restrict__ scores,
    unsigned long long* __restrict__ peaks,
    unsigned int* __restrict__ pcount)
{
    const int b = blockIdx.z;
    const int tx = threadIdx.x & 15;
    const int ty = threadIdx.x >> 4;
    const int x = blockIdx.x * 64 + tx * 4;
    const int y = blockIdx.y * 64 + ty * 4;
    const float* img = scores + (size_t)b * NPIX;
    const float4* imgq = (const float4*)img;

    __shared__ unsigned long long lbuf[512];
    __shared__ unsigned int lcnt;
    __shared__ unsigned int lbase;
    if (threadIdx.x == 0) lcnt = 0;
    __syncthreads();

    const int q = x >> 2;
    const int qm = (q > 0) ? q - 1 : 0;
    const int qp = (q < WW / 4 - 1) ? q + 1 : WW / 4 - 1;

    float hm[8][4];
    float c4[4][4];

#pragma unroll
    for (int j = 0; j < 8; ++j) {
        int gy = y - 2 + j;
        gy = gy < 0 ? 0 : (gy > HH - 1 ? HH - 1 : gy);
        const float4* rowq = imgq + (size_t)gy * (WW / 4);
        const float4 A = rowq[qm];
        const float4 B = rowq[q];
        const float4 C = rowq[qp];
        const float v[12] = {A.x, A.y, A.z, A.w, B.x, B.y, B.z, B.w,
                             C.x, C.y, C.z, C.w};
        float aa[8];
#pragma unroll
        for (int k = 0; k < 8; ++k) aa[k] = fmaxf(v[k + 2], v[k + 3]);
#pragma unroll
        for (int i = 0; i < 4; ++i)
            hm[j][i] = fmaxf(fmaxf(aa[i], aa[i + 2]), v[i + 6]);
        if (j >= 2 && j <= 5) {
#pragma unroll
            for (int i = 0; i < 4; ++i) c4[j - 2][i] = v[i + 4];
        }
    }

#pragma unroll
    for (int r = 0; r < 4; ++r) {
        const int oy = y + r;
        const bool yok = (oy >= 2) && (oy <= HH - 3);
#pragma unroll
        for (int i = 0; i < 4; ++i) {
            const float vm = fmaxf(fmaxf(fmaxf(hm[r][i], hm[r + 1][i]),
                                         fmaxf(hm[r + 2][i], hm[r + 3][i])),
                                   hm[r + 4][i]);
            const float cv = c4[r][i];
            const int col = x + i;
            if (yok && col >= 2 && col <= WW - 3 && cv == vm) {
                unsigned int pos = atomicAdd(&lcnt, 1u);
                if (pos < 512u) {
                    unsigned int idx = (unsigned int)(oy * WW + col);
                    lbuf[pos] = ((unsigned long long)__float_as_uint(cv) << 32) |
                                (unsigned long long)(~idx);
                }
            }
        }
    }
    __syncthreads();

    unsigned int cnt = lcnt;
    if (cnt > 512u) cnt = 512u;
    if (threadIdx.x == 0) lbase = atomicAdd(&pcount[b], cnt);
    __syncthreads();
    const unsigned int gbase = lbase;
    for (unsigned int s = threadIdx.x; s < cnt; s += 256) {
        unsigned int gpos = gbase + s;
        if (gpos < PEAK_CAP) peaks[(size_t)b * PEAK_CAP + gpos] = lbuf[s];
    }
}

// ---------------- K1b: per-chunk LDS-private histogram ----------------
// grid (NCHUNK, BATCH), block 1024 (R6: 4x parallelism vs 256).
__global__ __launch_bounds__(1024) void k_hist(
    const unsigned long long* __restrict__ peaks,
    const unsigned int* __restrict__ pcount,
    unsigned int* __restrict__ partials)
{
    const int b = blockIdx.y;
    const int blk = blockIdx.x;
    unsigned int n = pcount[b];
    if (n > PEAK_CAP) n = PEAK_CAP;
    const unsigned int base = blk * CHUNK;
    if (base >= n) return;

    __shared__ unsigned int h[NB / 2];   // 32 KB packed u16 pairs
    for (int w = threadIdx.x; w < NB / 2; w += 1024) h[w] = 0u;
    __syncthreads();

    const unsigned int end = (base + CHUNK < n) ? base + CHUNK : n;
    for (unsigned int i = base + threadIdx.x; i < end; i += 1024) {
        unsigned long long key = peaks[(size_t)b * PEAK_CAP + i];
        float v = __uint_as_float((unsigned int)(key >> 32));
        int bk = bucket_of(v);
        atomicAdd(&h[bk >> 1], (bk & 1) ? 0x10000u : 1u);
    }
    __syncthreads();

    unsigned int* dst = partials + ((size_t)(b * NCHUNK + blk)) * (NB / 2);
    for (int w = threadIdx.x; w < NB / 2; w += 1024) dst[w] = h[w];
}

// ---------------- K2: merge partials (coalesced, LDS) + suffix scan ----------------
// grid: (8), block 256. R6: coalesced merge into packed LDS hist (the old
// version's 128B-stride global reads on 8 blocks were latency-serialized).
__global__ __launch_bounds__(256) void k_scan(
    const unsigned int* __restrict__ partials,
    const unsigned int* __restrict__ pcount,
    unsigned int* __restrict__ hist,
    unsigned int* __restrict__ SA,
    unsigned int* __restrict__ ncand,
    unsigned int* __restrict__ bstar)
{
    const int b = blockIdx.x;
    unsigned int n = pcount[b];
    if (n > PEAK_CAP) n = PEAK_CAP;
    const int nblk = (int)((n + CHUNK - 1) / CHUNK);
    unsigned int* sab = SA + b * NB;
    const int t = threadIdx.x;

    __shared__ unsigned int h[NB / 2];   // packed lo | hi<<16, 32 KB
    __shared__ unsigned int ps[256];
    __shared__ int bmax;

    // coalesced merge: consecutive threads -> consecutive words
    for (int w = t; w < NB / 2; w += 256) {
        unsigned int lo = 0, hi = 0;
        for (int k = 0; k < nblk; ++k) {
            unsigned int p = partials[(size_t)(b * NCHUNK + k) * (NB / 2) + w];
            lo += p & 0xFFFFu;
            hi += p >> 16;
        }
        h[w] = lo | (hi << 16);
        ((uint2*)hist)[(size_t)b * (NB / 2) + w] = make_uint2(lo, hi);
    }
    __syncthreads();

    // per-thread 64-bin total; rotated index -> conflict-free LDS
    unsigned int sum = 0;
    for (int kk = 0; kk < 32; ++kk) {
        const int k = (kk + t) & 31;
        const unsigned int p = h[t * 32 + k];
        sum += (p & 0xFFFFu) + (p >> 16);
    }
    ps[t] = sum;
    __syncthreads();
    for (int off = 1; off < 256; off <<= 1) {
        unsigned int v = (t + off < 256) ? ps[t + off] : 0u;
        __syncthreads();
        ps[t] += v;
        __syncthreads();
    }
    unsigned int run = ps[t] - sum;  // strictly above this thread's chunk
    int bst_local = -1;
    for (int i = 63; i >= 0; --i) {
        const int bin = t * 64 + i;
        const unsigned int w = h[t * 32 + (i >> 1)];
        const unsigned int hv = (i & 1) ? (w >> 16) : (w & 0xFFFFu);
        sab[bin] = run;
        if (run + hv >= TOPK && bst_local < 0) bst_local = bin;
        run += hv;
    }
    if (t == 0) bmax = -1;
    __syncthreads();
    if (bst_local >= 0) atomicMax(&bmax, bst_local);
    __syncthreads();
    if (t == 0) {
        const int Bs = bmax < 0 ? 0 : bmax;
        bstar[b] = (unsigned int)Bs;
        const unsigned int w = h[Bs >> 1];
        const unsigned int hv = (Bs & 1) ? (w >> 16) : (w & 0xFFFFu);
        unsigned int nc = sab[Bs] + hv;
        if (nc > CAND_CAP) nc = CAND_CAP;
        ncand[b] = nc;
    }
}

// ---------------- K3: filter -> bucket-grouped cands, aggregated atomics ----------------
// grid (PEAK_CAP/FCHUNK=24, 8), block 256. Two-pass over an 8192-key chunk:
// count winners per bin in LDS, ONE global atomic per (block,bin) to reserve,
// then scatter. Kills the hot-line per-key global atomics of R5.
__global__ __launch_bounds__(256) void k_filter(
    const unsigned long long* __restrict__ peaks,
    const unsigned int* __restrict__ pcount,
    const unsigned int* __restrict__ bstar,
    const unsigned int* __restrict__ SA,
    unsigned int* __restrict__ fill,
    unsigned long long* __restrict__ cands)
{
    const int b = blockIdx.y;
    unsigned int n = pcount[b];
    if (n > PEAK_CAP) n = PEAK_CAP;
    const unsigned int base = blockIdx.x * FCHUNK;
    if (base >= n) return;
    const unsigned int end = (base + FCHUNK < n) ? base + FCHUNK : n;
    const unsigned int bs = bstar[b];
    const unsigned long long* pb = peaks + (size_t)b * PEAK_CAP;
    unsigned long long* cb = cands + (size_t)b * CAND_CAP;

    __shared__ unsigned int cnt[LBINS];  // pass1 counts -> global bases
    __shared__ unsigned int off[LBINS];  // pass2 running offsets
    for (int j = threadIdx.x; j < LBINS; j += 256) { cnt[j] = 0u; off[j] = 0u; }
    __syncthreads();

    // pass 1: count winners per LDS-managed bin (fallback: direct global)
    for (unsigned int i = base + threadIdx.x; i < end; i += 256) {
        const unsigned long long key = pb[i];
        const float v = __uint_as_float((unsigned int)(key >> 32));
        const int bk = bucket_of(v);
        if ((unsigned int)bk < bs) continue;
        if (bk >= LO_BIN) {
            atomicAdd(&cnt[bk - LO_BIN], 1u);
        } else {
            unsigned int pos = SA[b * NB + bk] + atomicAdd(&fill[b * NB + bk], 1u);
            if (pos < CAND_CAP) cb[pos] = key;
        }
    }
    __syncthreads();

    // reserve: one global atomic per nonzero bin
    for (int j = threadIdx.x; j < LBINS; j += 256) {
        const unsigned int c = cnt[j];
        if (c) cnt[j] = atomicAdd(&fill[b * NB + LO_BIN + j], c);
    }
    __syncthreads();

    // pass 2: scatter
    for (unsigned int i = base + threadIdx.x; i < end; i += 256) {
        const unsigned long long key = pb[i];
        const float v = __uint_as_float((unsigned int)(key >> 32));
        const int bk = bucket_of(v);
        if ((unsigned int)bk < bs || bk < LO_BIN) continue;
        const unsigned int l = atomicAdd(&off[bk - LO_BIN], 1u);
        const unsigned int pos = SA[b * NB + bk] + cnt[bk - LO_BIN] + l;
        if (pos < CAND_CAP) cb[pos] = key;
    }
}

// ---------------- K4: exact rank within bucket + per-keypoint outputs ----------------
// grid: (64, 8), block 256
__global__ __launch_bounds__(256) void k_out(
    const float* __restrict__ scores,
    const unsigned long long* __restrict__ cands,
    const unsigned int* __restrict__ ncand,
    const unsigned int* __restrict__ SA,
    const unsigned int* __restrict__ hist,
    float* __restrict__ out)
{
    const int b = blockIdx.y;
    unsigned int n = ncand[b];
    if (n > CAND_CAP) n = CAND_CAP;
    const int base = blockIdx.x * 256;
    const unsigned long long* cb = cands + (size_t)b * CAND_CAP;

    __shared__ unsigned long long seg[1024];  // window [base-384, base+640)
    for (int t = threadIdx.x; t < 1024; t += 256) {
        int gi = base - 384 + t;
        unsigned long long v = 0ull;
        if (gi >= 0 && gi < (int)n) v = cb[gi];
        seg[t] = v;
    }
    __syncthreads();

    unsigned int ci = base + threadIdx.x;
    if (ci >= n) return;

    const unsigned long long key = cb[ci];
    float v = __uint_as_float((unsigned int)(key >> 32));
    const int bk = bucket_of(v);
    const unsigned int seg0 = SA[b * NB + bk];
    const unsigned int len = hist[b * NB + bk];

    unsigned int r = 0;
    if ((int)seg0 >= base - 384 && (int)(seg0 + len) <= base + 640) {
        const int s0 = (int)seg0 - (base - 384);
        for (unsigned int j = 0; j < len; ++j)
            r += (seg[s0 + j] > key) ? 1u : 0u;
    } else {
#pragma unroll 4
        for (unsigned int j = 0; j < len; ++j)
            r += (cb[seg0 + j] > key) ? 1u : 0u;
    }
    const unsigned int rank = seg0 + r;
    if (rank >= TOPK) return;

    const unsigned int idx = ~((unsigned int)(key & 0xFFFFFFFFull));
    const int ky = (int)(idx >> 11);
    const int kx = (int)(idx & (WW - 1));
    const float* img = scores + (size_t)b * NPIX;

    float patch[25];
#pragma unroll
    for (int dy = 0; dy < 5; ++dy) {
#pragma unroll
        for (int dx = 0; dx < 5; ++dx) {
            patch[dy * 5 + dx] = img[(size_t)(ky + dy - 2) * WW + (kx + dx - 2)];
        }
    }
    float mx = patch[0];
#pragma unroll
    for (int p = 1; p < 25; ++p) mx = fmaxf(mx, patch[p]);

    float e[25];
    float s = 0.0f, sx = 0.0f, sy = 0.0f;
#pragma unroll
    for (int p = 0; p < 25; ++p) {
        float ex = expf((patch[p] - mx) * 10.0f);
        e[p] = ex;
        s += ex;
        sx += ex * (float)(p % 5 - 2);
        sy += ex * (float)(p / 5 - 2);
    }
    const float xx = sx / s;
    const float yy = sy / s;

    float dsum = 0.0f;
#pragma unroll
    for (int p = 0; p < 25; ++p) {
        float ddx = ((float)(p % 5 - 2) - xx) * 0.5f;
        float ddy = ((float)(p / 5 - 2) - yy) * 0.5f;
        dsum += e[p] * (ddx * ddx + ddy * ddy);
    }
    const float disp = dsum / s;

    const float kxy_x = ((float)kx + xx) / (float)(WW - 1) * 2.0f - 1.0f;
    const float kxy_y = ((float)ky + yy) / (float)(HH - 1) * 2.0f - 1.0f;

    const float px = (kxy_x + 1.0f) * 0.5f * (float)(WW - 1);
    const float py = (kxy_y + 1.0f) * 0.5f * (float)(HH - 1);
    int x0 = (int)floorf(px); x0 = x0 < 0 ? 0 : (x0 > WW - 1 ? WW - 1 : x0);
    int y0 = (int)floorf(py); y0 = y0 < 0 ? 0 : (y0 > HH - 1 ? HH - 1 : y0);
    int x1 = x0 + 1 > WW - 1 ? WW - 1 : x0 + 1;
    int y1 = y0 + 1 > HH - 1 ? HH - 1 : y0 + 1;
    const float wx = px - (float)x0;
    const float wy = py - (float)y0;
    const float v00 = img[(size_t)y0 * WW + x0];
    const float v01 = img[(size_t)y0 * WW + x1];
    const float v10 = img[(size_t)y1 * WW + x0];
    const float v11 = img[(size_t)y1 * WW + x1];
    const float ksc = v00 * (1.0f - wx) * (1.0f - wy) + v01 * wx * (1.0f - wy)
                    + v10 * (1.0f - wx) * wy + v11 * wx * wy;

    const size_t ok = (size_t)b * TOPK + rank;
    out[2 * ok]     = kxy_x;
    out[2 * ok + 1] = kxy_y;
    out[(size_t)BATCH * TOPK * 2 + ok] = ksc;
    out[(size_t)BATCH * TOPK * 3 + ok] = disp;
}

extern "C" void kernel_launch(void* const* d_in, const int* in_sizes, int n_in,
                              void* d_out, int out_size, void* d_ws, size_t ws_size,
                              hipStream_t stream) {
    const float* scores = (const float*)d_in[0];
    float* out = (float*)d_out;
    char* ws = (char*)d_ws;

    unsigned long long* peaks = (unsigned long long*)(ws + OFF_PEAKS);
    unsigned long long* cands = (unsigned long long*)(ws + OFF_CANDS);
    unsigned int* hist   = (unsigned int*)(ws + OFF_HIST);
    unsigned int* SA     = (unsigned int*)(ws + OFF_SA);
    unsigned int* fill   = (unsigned int*)(ws + OFF_FILL);
    unsigned int* pcount = (unsigned int*)(ws + OFF_PCOUNT);
    unsigned int* ncand  = (unsigned int*)(ws + OFF_NCAND);
    unsigned int* bstar  = (unsigned int*)(ws + OFF_BSTAR);
    unsigned int* part   = (unsigned int*)(ws + OFF_PART);

    // zero fill + counters only (hist/SA are fully overwritten by k_scan)
    hipMemsetAsync(ws + OFF_FILL, 0, (size_t)(OFF_END - OFF_FILL), stream);

    k_nms<<<dim3(WW / 64, HH / 64, BATCH), 256, 0, stream>>>(scores, peaks, pcount);
    k_hist<<<dim3(NCHUNK, BATCH), 1024, 0, stream>>>(peaks, pcount, part);
    k_scan<<<dim3(BATCH), 256, 0, stream>>>(part, pcount, hist, SA, ncand, bstar);
    k_filter<<<dim3(PEAK_CAP / FCHUNK, BATCH), 256, 0, stream>>>(peaks, pcount, bstar, SA, fill, cands);
    k_out<<<dim3(CAND_CAP / 256, BATCH), 256, 0, stream>>>(scores, cands, ncand, SA, hist, out);
}